// Round 3
// baseline (1572.266 us; speedup 1.0000x reference)
//
#include <hip/hip_runtime.h>
#include <hip/hip_bf16.h>
#include <hip/hip_fp16.h>
#include <math.h>

#define N_NODES 100000
#define IN_DIM 64
#define EMBED_DIM 128
#define EDGE_DIM 32
#define N_EDGES 1600000

#define NB 391            // node buckets of 256 nodes: bucket = n >> 8
#define SLICE_STRIDE 64   // f32 slice row stride (256 rows x 64 = 64 KB LDS)

typedef __attribute__((ext_vector_type(8))) short bf16x8;
typedef __attribute__((ext_vector_type(4))) float f32x4;

__device__ __forceinline__ ushort f2bf(float f) {
    union { float f; uint i; } v; v.f = f;
    uint x = v.i;
    return (ushort)((x + 0x7fffu + ((x >> 16) & 1u)) >> 16);  // RNE
}

// ---------------------------------------------------------------------------
// x -> f16 (halves gather footprint; L3-resident node features)
// ---------------------------------------------------------------------------
__global__ __launch_bounds__(256) void cvt_x_kernel(
    const float* __restrict__ x, __half* __restrict__ xh)
{
    const int i = blockIdx.x * blockDim.x + threadIdx.x;
    if (i < N_NODES * IN_DIM / 4) {
        float4 v = ((const float4*)x)[i];
        ((__half2*)xh)[2 * i]     = __floats2half2_rn(v.x, v.y);
        ((__half2*)xh)[2 * i + 1] = __floats2half2_rn(v.z, v.w);
    }
}

// ---------------------------------------------------------------------------
// ea -> bf16 (one 64B line per edge row for the random gathers in agg)
// ---------------------------------------------------------------------------
__global__ __launch_bounds__(256) void cvt_ea_kernel(
    const float* __restrict__ ea, ushort* __restrict__ eab)
{
    const int i = blockIdx.x * blockDim.x + threadIdx.x;
    if (i < N_EDGES * EDGE_DIM / 4) {
        float4 v = ((const float4*)ea)[i];
        ushort4 o;
        o.x = f2bf(v.x); o.y = f2bf(v.y); o.z = f2bf(v.z); o.w = f2bf(v.w);
        ((ushort4*)eab)[i] = o;
    }
}

// ---------------------------------------------------------------------------
// Bucket histogram: 782 counters, LDS-staged per block -> tiny global flush
// ---------------------------------------------------------------------------
__global__ __launch_bounds__(256) void hist_kernel(
    const int* __restrict__ ei, int* __restrict__ gcnt)
{
    __shared__ int cnt[2 * NB];
    for (int i = threadIdx.x; i < 2 * NB; i += 256) cnt[i] = 0;
    __syncthreads();
    for (int e = blockIdx.x * 256 + threadIdx.x; e < N_EDGES; e += gridDim.x * 256) {
        const int s = ei[e];
        const int d = ei[N_EDGES + e];
        atomicAdd(&cnt[d >> 8], 1);
        atomicAdd(&cnt[NB + (s >> 8)], 1);
    }
    __syncthreads();
    for (int i = threadIdx.x; i < 2 * NB; i += 256)
        if (cnt[i]) atomicAdd(&gcnt[i], cnt[i]);
}

// ---------------------------------------------------------------------------
// Scan: two serial 391-entry prefix sums (tiny) -> gbase, gpos
// ---------------------------------------------------------------------------
__global__ __launch_bounds__(256) void scan_kernel(
    const int* __restrict__ gcnt, int* __restrict__ gbase, int* __restrict__ gpos)
{
    __shared__ int c[2 * NB];
    __shared__ int b[2 * NB];
    for (int i = threadIdx.x; i < 2 * NB; i += 256) c[i] = gcnt[i];
    __syncthreads();
    if (threadIdx.x == 0) {
        int acc = 0;
        for (int i = 0; i < NB; ++i) { b[i] = acc; acc += c[i]; }
    } else if (threadIdx.x == 64) {
        int acc = 0;
        for (int i = NB; i < 2 * NB; ++i) { b[i] = acc; acc += c[i]; }
    }
    __syncthreads();
    for (int i = threadIdx.x; i < 2 * NB; i += 256) {
        gbase[i] = b[i];
        gpos[i]  = b[i];
    }
}

// ---------------------------------------------------------------------------
// Scatter: 8192 edges per block. LDS histogram -> one global claim per
// (block,bucket) -> fire-and-forget 8B record stores at block-consecutive
// indices (L2 write-combines). Record = {eid, other | local_row<<24}.
// ---------------------------------------------------------------------------
__global__ __launch_bounds__(256) void scatter_kernel(
    const int* __restrict__ ei, int* __restrict__ gpos, int2* __restrict__ perm)
{
    __shared__ int cnt[2 * NB];
    __shared__ int base[2 * NB];
    for (int i = threadIdx.x; i < 2 * NB; i += 256) cnt[i] = 0;
    __syncthreads();
    const int e0 = blockIdx.x * 8192;
    for (int k = 0; k < 32; ++k) {
        const int e = e0 + k * 256 + threadIdx.x;
        if (e < N_EDGES) {
            const int s = ei[e];
            const int d = ei[N_EDGES + e];
            atomicAdd(&cnt[d >> 8], 1);
            atomicAdd(&cnt[NB + (s >> 8)], 1);
        }
    }
    __syncthreads();
    for (int i = threadIdx.x; i < 2 * NB; i += 256) {
        base[i] = atomicAdd(&gpos[i], cnt[i]);
        cnt[i] = 0;
    }
    __syncthreads();
    for (int k = 0; k < 32; ++k) {
        const int e = e0 + k * 256 + threadIdx.x;
        if (e < N_EDGES) {
            const int s = ei[e];
            const int d = ei[N_EDGES + e];
            const int bi = d >> 8;
            const int p = base[bi] + atomicAdd(&cnt[bi], 1);
            perm[p] = make_int2(e, s | ((d & 255) << 24));
            const int bo = NB + (s >> 8);
            const int q = base[bo] + atomicAdd(&cnt[bo], 1);
            perm[(size_t)N_EDGES + q] = make_int2(e, d | ((s & 255) << 24));
        }
    }
}

// ---------------------------------------------------------------------------
// Bucket aggregation: one block per (bucket, dir). 64 KB f32 slice in LDS,
// MFMA edge-linear (identical math to the verified round-1 edge kernel),
// ds_add_f32 accumulation, single coalesced slice writeback. NO global
// atomics. Records prefetched one iteration ahead.
// ---------------------------------------------------------------------------
__global__ __launch_bounds__(512) void bucket_agg_kernel(
    const __half* __restrict__ xh, const ushort* __restrict__ eab,
    const float* __restrict__ We_in, const float* __restrict__ be_in,
    const float* __restrict__ We_out, const float* __restrict__ be_out,
    const int* __restrict__ gbase, const int* __restrict__ gcnt,
    const int2* __restrict__ perm,
    float* __restrict__ agg_in, float* __restrict__ agg_out)
{
    const int lane = threadIdx.x & 63;
    const int r = lane & 15;
    const int h = lane >> 4;
    const int w = threadIdx.x >> 6;     // 0..7

    const int dir = blockIdx.x & 1;
    const int b   = blockIdx.x >> 1;

    const float* We  = dir ? We_out : We_in;
    const float* be  = dir ? be_out : be_in;
    float* agg       = dir ? agg_out : agg_in;
    const int2* pm   = perm + (size_t)dir * N_EDGES;

    __shared__ float slice[256 * SLICE_STRIDE];   // 64 KB

    for (int i = threadIdx.x; i < 256 * SLICE_STRIDE; i += 512) slice[i] = 0.f;

    // B fragments (permuted cols cp = (t>>1)*32 + 2r + (t&1)) + bias
    bf16x8 bW[4];
    float beV[4];
#pragma unroll
    for (int t = 0; t < 4; ++t) {
        const int cp = ((t >> 1) << 5) + (r << 1) + (t & 1);
        const float* p = We + (h * 8) * 64 + cp;
        bf16x8 bv;
#pragma unroll
        for (int j = 0; j < 8; ++j) bv[j] = (short)f2bf(p[j * 64]);
        bW[t] = bv;
        beV[t] = be[cp];
    }

    __syncthreads();

    const int rs = gbase[dir * NB + b];
    const int re = rs + gcnt[dir * NB + b];

    int base = rs + w * 16;
    int2 rec = make_int2(0, 0);
    if (base < re) {
        const int slot = base + r;
        rec = pm[slot < re ? slot : re - 1];
    }

    for (; base < re; base += 128) {
        // prefetch next iteration's record
        const int nbase = base + 128;
        int2 recn = rec;
        if (nbase < re) {
            const int slot = nbase + r;
            recn = pm[slot < re ? slot : re - 1];
        }

        const bf16x8 a = *(const bf16x8*)(eab + (size_t)rec.x * 32 + h * 8);

        f32x4 C[4];
#pragma unroll
        for (int t = 0; t < 4; ++t) {
            f32x4 z = {0.f, 0.f, 0.f, 0.f};
            C[t] = __builtin_amdgcn_mfma_f32_16x16x32_bf16(a, bW[t], z, 0, 0, 0);
        }

        const int own = rec.y;
#pragma unroll
        for (int i = 0; i < 4; ++i) {
            const int m = h * 4 + i;                 // C/D row = edge slot
            const int ow = __shfl(own, m, 64);
            const int other = ow & 0x00FFFFFF;
            const int ln = ((unsigned)ow) >> 24;     // local row in bucket
            const bool valid = (base + m) < re;
            float* srow = slice + ln * SLICE_STRIDE;
#pragma unroll
            for (int tp = 0; tp < 2; ++tp) {
                const __half2 xs =
                    *(const __half2*)(xh + (size_t)other * 64 + 32 * tp + 2 * r);
                float m0 = fmaxf(__low2float(xs)  + C[2 * tp][i]     + beV[2 * tp],     0.f);
                float m1 = fmaxf(__high2float(xs) + C[2 * tp + 1][i] + beV[2 * tp + 1], 0.f);
                if (valid) {
                    atomicAdd(srow + 32 * tp + 2 * r,     m0);
                    atomicAdd(srow + 32 * tp + 2 * r + 1, m1);
                }
            }
        }
        rec = recn;
    }

    __syncthreads();

    // Coalesced writeback: 256 rows x 16 float4
    const int n0 = b << 8;
    for (int idx = threadIdx.x; idx < 256 * 16; idx += 512) {
        const int row = idx >> 4;
        const int c4  = idx & 15;
        const int n = n0 + row;
        if (n < N_NODES)
            *(float4*)(agg + (size_t)n * 64 + c4 * 4) =
                *(const float4*)(slice + row * SLICE_STRIDE + c4 * 4);
    }
}

// ---------------------------------------------------------------------------
// Fallback edge stage (round-1 f16-atomic version) for small workspaces.
// ---------------------------------------------------------------------------
__global__ __launch_bounds__(256) void edge_kernel(
    const __half* __restrict__ xh, const int* __restrict__ ei,
    const float* __restrict__ ea,
    const float* __restrict__ We_in, const float* __restrict__ be_in,
    const float* __restrict__ We_out, const float* __restrict__ be_out,
    __half* __restrict__ agg_in, __half* __restrict__ agg_out)
{
    const int lane = threadIdx.x & 63;
    const int r = lane & 15;
    const int h = lane >> 4;
    const int wave = threadIdx.x >> 6;

    bf16x8 bIn[4], bOut[4];
    float beI[4], beO[4];
#pragma unroll
    for (int t = 0; t < 4; ++t) {
        const int cp = ((t >> 1) << 5) + (r << 1) + (t & 1);
        const float* p1 = We_in  + (h * 8) * 64 + cp;
        const float* p2 = We_out + (h * 8) * 64 + cp;
        bf16x8 b1v, b2v;
#pragma unroll
        for (int j = 0; j < 8; ++j) {
            b1v[j] = (short)f2bf(p1[j * 64]);
            b2v[j] = (short)f2bf(p2[j * 64]);
        }
        bIn[t] = b1v; bOut[t] = b2v;
        beI[t] = be_in[cp];
        beO[t] = be_out[cp];
    }

    const int nGroups = N_EDGES / 16;
    const int stride = gridDim.x * 4;
    for (int g = blockIdx.x * 4 + wave; g < nGroups; g += stride) {
        const int e0 = g * 16;
        const float* ap = ea + (size_t)(e0 + r) * 32 + h * 8;
        float4 av0 = *(const float4*)ap;
        float4 av1 = *(const float4*)(ap + 4);
        bf16x8 a;
        a[0] = (short)f2bf(av0.x); a[1] = (short)f2bf(av0.y);
        a[2] = (short)f2bf(av0.z); a[3] = (short)f2bf(av0.w);
        a[4] = (short)f2bf(av1.x); a[5] = (short)f2bf(av1.y);
        a[6] = (short)f2bf(av1.z); a[7] = (short)f2bf(av1.w);

        f32x4 cIn[4], cOut[4];
#pragma unroll
        for (int t = 0; t < 4; ++t) {
            f32x4 z = {0.f, 0.f, 0.f, 0.f};
            cIn[t]  = __builtin_amdgcn_mfma_f32_16x16x32_bf16(a, bIn[t],  z, 0, 0, 0);
            cOut[t] = __builtin_amdgcn_mfma_f32_16x16x32_bf16(a, bOut[t], z, 0, 0, 0);
        }

        const int4 s4 = *(const int4*)(ei + e0 + h * 4);
        const int4 d4 = *(const int4*)(ei + N_EDGES + e0 + h * 4);
        const int ss[4] = {s4.x, s4.y, s4.z, s4.w};
        const int dd[4] = {d4.x, d4.y, d4.z, d4.w};

#pragma unroll
        for (int i = 0; i < 4; ++i) {
            const int s = ss[i];
            const int d = dd[i];
#pragma unroll
            for (int tp = 0; tp < 2; ++tp) {
                const int coff = 32 * tp + 2 * r;
                __half2 xs = *(const __half2*)(xh + (size_t)s * 64 + coff);
                float m0 = fmaxf(__low2float(xs)  + cIn[2 * tp][i]     + beI[2 * tp],     0.0f);
                float m1 = fmaxf(__high2float(xs) + cIn[2 * tp + 1][i] + beI[2 * tp + 1], 0.0f);
                if (m0 != 0.0f || m1 != 0.0f)
                    unsafeAtomicAdd((__half2*)(agg_in + (size_t)d * 64 + coff),
                                    __floats2half2_rn(m0, m1));
                __half2 xd = *(const __half2*)(xh + (size_t)d * 64 + coff);
                float n0 = fmaxf(__low2float(xd)  + cOut[2 * tp][i]     + beO[2 * tp],     0.0f);
                float n1 = fmaxf(__high2float(xd) + cOut[2 * tp + 1][i] + beO[2 * tp + 1], 0.0f);
                if (n0 != 0.0f || n1 != 0.0f)
                    unsafeAtomicAdd((__half2*)(agg_out + (size_t)s * 64 + coff),
                                    __floats2half2_rn(n0, n1));
            }
        }
    }
}

// ---------------------------------------------------------------------------
// Node stage (templated on agg dtype: f32 for bucket path, f16 for fallback)
// ---------------------------------------------------------------------------
#define T_STRIDE 136

__device__ __forceinline__ void load8f(const float* __restrict__ p, float* o) {
    float4 a = *(const float4*)p;
    float4 b = *(const float4*)(p + 4);
    o[0] = a.x; o[1] = a.y; o[2] = a.z; o[3] = a.w;
    o[4] = b.x; o[5] = b.y; o[6] = b.z; o[7] = b.w;
}
__device__ __forceinline__ void load8f(const __half* __restrict__ p, float* o) {
#pragma unroll
    for (int j = 0; j < 4; ++j) {
        __half2 g = *(const __half2*)(p + 2 * j);
        o[2 * j]     = __low2float(g);
        o[2 * j + 1] = __high2float(g);
    }
}

template<typename AggT>
__device__ __forceinline__ void gine_mlp(
    const float* __restrict__ x, const AggT* __restrict__ agg,
    const float* __restrict__ W1, const float* __restrict__ b1,
    const float* __restrict__ W2,
    int n0, int r, int h, ushort* Tw, f32x4 hAcc[8])
{
    bf16x8 a0[2];
#pragma unroll
    for (int half_ = 0; half_ < 2; ++half_) {
        const int kb = half_ * 32 + h * 8;
        float xv[8], gv[8];
        load8f(x   + (size_t)(n0 + r) * 64 + kb, xv);
        load8f(agg + (size_t)(n0 + r) * 64 + kb, gv);
        bf16x8 v;
#pragma unroll
        for (int j = 0; j < 8; ++j) v[j] = (short)f2bf(xv[j] + gv[j]);
        a0[half_] = v;
    }

    __threadfence_block();

    // Layer 1: T = gelu(H0 @ W1 + b1) -> LDS (bf16)
#pragma unroll
    for (int t = 0; t < 8; ++t) {
        const float* w1p = W1 + (h * 8) * 128 + 16 * t + r;
        bf16x8 b0v, b1v;
#pragma unroll
        for (int j = 0; j < 8; ++j) {
            b0v[j] = (short)f2bf(w1p[j * 128]);
            b1v[j] = (short)f2bf(w1p[4096 + j * 128]);
        }
        f32x4 acc = {0.f, 0.f, 0.f, 0.f};
        acc = __builtin_amdgcn_mfma_f32_16x16x32_bf16(a0[0], b0v, acc, 0, 0, 0);
        acc = __builtin_amdgcn_mfma_f32_16x16x32_bf16(a0[1], b1v, acc, 0, 0, 0);
        float bias = b1[16 * t + r];
#pragma unroll
        for (int i = 0; i < 4; ++i) {
            float v = acc[i] + bias;
            float g = 0.5f * v * (1.0f + erff(v * 0.70710678118654752f));
            Tw[(h * 4 + i) * T_STRIDE + 16 * t + r] = f2bf(g);
        }
    }

    __threadfence_block();

    // Layer 2: h = T @ W2
    bf16x8 aT[4];
#pragma unroll
    for (int ks = 0; ks < 4; ++ks)
        aT[ks] = *(const bf16x8*)(Tw + r * T_STRIDE + ks * 32 + h * 8);
#pragma unroll
    for (int t = 0; t < 8; ++t) {
        const float* w2p = W2 + (h * 8) * 128 + 16 * t + r;
        f32x4 acc = {0.f, 0.f, 0.f, 0.f};
#pragma unroll
        for (int ks = 0; ks < 4; ++ks) {
            bf16x8 bv;
#pragma unroll
            for (int j = 0; j < 8; ++j) bv[j] = (short)f2bf(w2p[(ks * 32 + j) * 128]);
            acc = __builtin_amdgcn_mfma_f32_16x16x32_bf16(aT[ks], bv, acc, 0, 0, 0);
        }
        hAcc[t] = acc;
    }
}

template<typename AggT>
__global__ __launch_bounds__(256) void node_kernel(
    const float* __restrict__ x,
    const AggT* __restrict__ agg_in, const AggT* __restrict__ agg_out,
    const float* __restrict__ W1_in, const float* __restrict__ b1_in,
    const float* __restrict__ W2_in, const float* __restrict__ b2_in,
    const float* __restrict__ W1_out, const float* __restrict__ b1_out,
    const float* __restrict__ W2_out, const float* __restrict__ b2_out,
    const float* __restrict__ Wr, const float* __restrict__ br,
    float* __restrict__ out)
{
    const int lane = threadIdx.x & 63;
    const int r = lane & 15;
    const int h = lane >> 4;
    const int wave = threadIdx.x >> 6;

    __shared__ __align__(16) ushort Tld[4][16 * T_STRIDE];
    ushort* Tw = &Tld[wave][0];

    const int g = blockIdx.x * 4 + wave;
    if (g >= N_NODES / 16) return;
    const int n0 = g * 16;

    f32x4 hIn[8], hOut[8];
    gine_mlp(x, agg_in,  W1_in,  b1_in,  W2_in,  n0, r, h, Tw, hIn);
    gine_mlp(x, agg_out, W1_out, b1_out, W2_out, n0, r, h, Tw, hOut);

    bf16x8 ar[2];
#pragma unroll
    for (int half_ = 0; half_ < 2; ++half_) {
        const float* xp = x + (size_t)(n0 + r) * 64 + half_ * 32 + h * 8;
        bf16x8 v;
#pragma unroll
        for (int j = 0; j < 8; ++j) v[j] = (short)f2bf(xp[j]);
        ar[half_] = v;
    }

#pragma unroll
    for (int t = 0; t < 8; ++t) {
        const float* wrp = Wr + (h * 8) * 128 + 16 * t + r;
        bf16x8 b0v, b1v;
#pragma unroll
        for (int j = 0; j < 8; ++j) {
            b0v[j] = (short)f2bf(wrp[j * 128]);
            b1v[j] = (short)f2bf(wrp[4096 + j * 128]);
        }
        f32x4 rt = {0.f, 0.f, 0.f, 0.f};
        rt = __builtin_amdgcn_mfma_f32_16x16x32_bf16(ar[0], b0v, rt, 0, 0, 0);
        rt = __builtin_amdgcn_mfma_f32_16x16x32_bf16(ar[1], b1v, rt, 0, 0, 0);

        const int c = 16 * t + r;
        float b2i = b2_in[c];
        float b2o = b2_out[c];
        float brv = br[c];
#pragma unroll
        for (int i = 0; i < 4; ++i) {
            float o = 0.5f * (hOut[t][i] + b2o) + 0.5f * (hIn[t][i] + b2i) + rt[i] + brv;
            out[(size_t)(n0 + h * 4 + i) * 128 + c] = o;
        }
    }
}

extern "C" void kernel_launch(void* const* d_in, const int* in_sizes, int n_in,
                              void* d_out, int out_size, void* d_ws, size_t ws_size,
                              hipStream_t stream) {
    const float* x      = (const float*)d_in[0];
    const int*   ei     = (const int*)d_in[1];
    const float* ea     = (const float*)d_in[2];
    const float* We_in  = (const float*)d_in[3];
    const float* be_in  = (const float*)d_in[4];
    const float* W1_in  = (const float*)d_in[5];
    const float* b1_in  = (const float*)d_in[6];
    const float* W2_in  = (const float*)d_in[7];
    const float* b2_in  = (const float*)d_in[8];
    const float* We_out = (const float*)d_in[9];
    const float* be_out = (const float*)d_in[10];
    const float* W1_out = (const float*)d_in[11];
    const float* b1_out = (const float*)d_in[12];
    const float* W2_out = (const float*)d_in[13];
    const float* b2_out = (const float*)d_in[14];
    const float* Wr     = (const float*)d_in[15];
    const float* br     = (const float*)d_in[16];

    const size_t EAB_B  = (size_t)N_EDGES * EDGE_DIM * 2;     // 102,400,000
    const size_t XH_B   = (size_t)N_NODES * IN_DIM * 2;       //  12,800,000
    const size_t AGG_B  = (size_t)N_NODES * IN_DIM * 4;       //  25,600,000
    const size_t PERM_B = (size_t)N_EDGES * 8;                //  12,800,000 (per dir)
    const size_t META_B = 3200;                               // 2*NB ints, padded
    const size_t NEED   = EAB_B + XH_B + 2 * AGG_B + 2 * PERM_B + 3 * META_B;

    if (ws_size >= NEED) {
        char* w = (char*)d_ws;
        ushort* eab    = (ushort*)w;   w += EAB_B;
        __half* xh     = (__half*)w;   w += XH_B;
        float* agg_in  = (float*)w;    w += AGG_B;
        float* agg_out = (float*)w;    w += AGG_B;
        int2* perm     = (int2*)w;     w += 2 * PERM_B;
        int* gcnt      = (int*)w;      w += META_B;
        int* gbase     = (int*)w;      w += META_B;
        int* gpos      = (int*)w;

        hipMemsetAsync(gcnt, 0, 2 * NB * sizeof(int), stream);

        cvt_x_kernel<<<(N_NODES * IN_DIM / 4 + 255) / 256, 256, 0, stream>>>(x, xh);
        cvt_ea_kernel<<<(N_EDGES * EDGE_DIM / 4 + 255) / 256, 256, 0, stream>>>(ea, eab);
        hist_kernel<<<512, 256, 0, stream>>>(ei, gcnt);
        scan_kernel<<<1, 256, 0, stream>>>(gcnt, gbase, gpos);
        scatter_kernel<<<(N_EDGES + 8191) / 8192, 256, 0, stream>>>(ei, gpos, perm);
        bucket_agg_kernel<<<2 * NB, 512, 0, stream>>>(
            xh, eab, We_in, be_in, We_out, be_out,
            gbase, gcnt, perm, agg_in, agg_out);
        node_kernel<float><<<(N_NODES / 16 + 3) / 4, 256, 0, stream>>>(
            x, agg_in, agg_out,
            W1_in, b1_in, W2_in, b2_in,
            W1_out, b1_out, W2_out, b2_out,
            Wr, br, (float*)d_out);
    } else {
        // Fallback: round-1 f16-atomic path (38.4 MB workspace)
        __half* agg_in  = (__half*)d_ws;
        __half* agg_out = agg_in + (size_t)N_NODES * IN_DIM;
        __half* xh      = agg_out + (size_t)N_NODES * IN_DIM;
        const size_t agg_bytes = (size_t)2 * N_NODES * IN_DIM * sizeof(__half);

        hipMemsetAsync(d_ws, 0, agg_bytes, stream);
        cvt_x_kernel<<<(N_NODES * IN_DIM / 4 + 255) / 256, 256, 0, stream>>>(x, xh);
        edge_kernel<<<2048, 256, 0, stream>>>(xh, ei, ea, We_in, be_in, We_out, be_out,
                                              agg_in, agg_out);
        node_kernel<__half><<<(N_NODES / 16 + 3) / 4, 256, 0, stream>>>(
            x, agg_in, agg_out,
            W1_in, b1_in, W2_in, b2_in,
            W1_out, b1_out, W2_out, b2_out,
            Wr, br, (float*)d_out);
    }
}

// Round 4
// 437.991 us; speedup vs baseline: 3.5897x; 3.5897x over previous
//
#include <hip/hip_runtime.h>
#include <hip/hip_bf16.h>
#include <hip/hip_fp16.h>
#include <math.h>

#define N_NODES 100000
#define IN_DIM 64
#define EMBED_DIM 128
#define EDGE_DIM 32
#define N_EDGES 1600000

typedef __attribute__((ext_vector_type(8))) short bf16x8;
typedef __attribute__((ext_vector_type(4))) float f32x4;

__device__ __forceinline__ ushort f2bf(float f) {
    union { float f; uint i; } v; v.f = f;
    uint x = v.i;
    return (ushort)((x + 0x7fffu + ((x >> 16) & 1u)) >> 16);  // RNE
}

// ---------------------------------------------------------------------------
// x -> f16 (halves gather footprint; matches pk_add_f16 layout)
// ---------------------------------------------------------------------------
__global__ __launch_bounds__(256) void cvt_x_kernel(
    const float* __restrict__ x, __half* __restrict__ xh)
{
    const int i = blockIdx.x * blockDim.x + threadIdx.x;
    if (i < N_NODES * IN_DIM / 4) {
        float4 v = ((const float4*)x)[i];
        ((__half2*)xh)[2 * i]     = __floats2half2_rn(v.x, v.y);
        ((__half2*)xh)[2 * i + 1] = __floats2half2_rn(v.z, v.w);
    }
}

// ---------------------------------------------------------------------------
// Edge stage (round-1 structure, software-pipelined):
//   agg_in[dst[e]]  += relu(x[src[e]] + ea[e]@We_in  + be_in)   (f16 atomics)
//   agg_out[src[e]] += relu(x[dst[e]] + ea[e]@We_out + be_out)  (f16 atomics)
// Pipeline per iteration:
//   1. prefetch next group's ea (2x float4) + ei (2x int4)
//   2. issue ALL 16 xh gathers for current group (addresses known from the
//      previous iteration's ei load -> latency hides under step 3)
//   3. bf16 cvt + 8 MFMAs
//   4. relu + pk_add_f16 atomics (non-returning; never waited on)
// B-frag cols permuted: cp(t,r)=(t>>1)*32+2r+(t&1) so MFMA blocks (2tp,2tp+1)
// form the lane-local half2 pair (32tp+2r, 32tp+2r+1).
// ---------------------------------------------------------------------------
__global__ __launch_bounds__(256) void edge_kernel(
    const __half* __restrict__ xh, const int* __restrict__ ei,
    const float* __restrict__ ea,
    const float* __restrict__ We_in, const float* __restrict__ be_in,
    const float* __restrict__ We_out, const float* __restrict__ be_out,
    __half* __restrict__ agg_in, __half* __restrict__ agg_out)
{
    const int lane = threadIdx.x & 63;
    const int r = lane & 15;
    const int h = lane >> 4;
    const int wave = threadIdx.x >> 6;

    // Preload B fragments (permuted cols) + biases
    bf16x8 bIn[4], bOut[4];
    float beI[4], beO[4];
#pragma unroll
    for (int t = 0; t < 4; ++t) {
        const int cp = ((t >> 1) << 5) + (r << 1) + (t & 1);
        const float* p1 = We_in  + (h * 8) * 64 + cp;
        const float* p2 = We_out + (h * 8) * 64 + cp;
        bf16x8 b1v, b2v;
#pragma unroll
        for (int j = 0; j < 8; ++j) {
            b1v[j] = (short)f2bf(p1[j * 64]);
            b2v[j] = (short)f2bf(p2[j * 64]);
        }
        bIn[t] = b1v; bOut[t] = b2v;
        beI[t] = be_in[cp];
        beO[t] = be_out[cp];
    }

    const int nGroups = N_EDGES / 16;
    const int stride = gridDim.x * 4;
    int g = blockIdx.x * 4 + wave;
    if (g >= nGroups) return;

    // Prologue: load ea + ei for the first group
    const float* ap0 = ea + (size_t)(g * 16 + r) * 32 + h * 8;
    float4 av0 = *(const float4*)ap0;
    float4 av1 = *(const float4*)(ap0 + 4);
    int4 s4 = *(const int4*)(ei + g * 16 + h * 4);
    int4 d4 = *(const int4*)(ei + N_EDGES + g * 16 + h * 4);

    while (true) {
        const int gn = g + stride;
        const bool more = gn < nGroups;

        // ---- 1. prefetch next group's ea + ei ----
        float4 nav0 = av0, nav1 = av1;
        int4 ns4 = s4, nd4 = d4;
        if (more) {
            const float* np = ea + (size_t)(gn * 16 + r) * 32 + h * 8;
            nav0 = *(const float4*)np;
            nav1 = *(const float4*)(np + 4);
            ns4 = *(const int4*)(ei + gn * 16 + h * 4);
            nd4 = *(const int4*)(ei + N_EDGES + gn * 16 + h * 4);
        }

        // ---- 2. issue all xh gathers for current group ----
        const int ss[4] = {s4.x, s4.y, s4.z, s4.w};
        const int dd[4] = {d4.x, d4.y, d4.z, d4.w};
        __half2 gs[4][2], gd[4][2];
#pragma unroll
        for (int i = 0; i < 4; ++i) {
#pragma unroll
            for (int tp = 0; tp < 2; ++tp) {
                gs[i][tp] = *(const __half2*)(xh + (size_t)ss[i] * 64 + 32 * tp + 2 * r);
                gd[i][tp] = *(const __half2*)(xh + (size_t)dd[i] * 64 + 32 * tp + 2 * r);
            }
        }

        // ---- 3. cvt + MFMA ----
        bf16x8 a;
        a[0] = (short)f2bf(av0.x); a[1] = (short)f2bf(av0.y);
        a[2] = (short)f2bf(av0.z); a[3] = (short)f2bf(av0.w);
        a[4] = (short)f2bf(av1.x); a[5] = (short)f2bf(av1.y);
        a[6] = (short)f2bf(av1.z); a[7] = (short)f2bf(av1.w);

        f32x4 cIn[4], cOut[4];
#pragma unroll
        for (int t = 0; t < 4; ++t) {
            f32x4 z = {0.f, 0.f, 0.f, 0.f};
            cIn[t]  = __builtin_amdgcn_mfma_f32_16x16x32_bf16(a, bIn[t],  z, 0, 0, 0);
            cOut[t] = __builtin_amdgcn_mfma_f32_16x16x32_bf16(a, bOut[t], z, 0, 0, 0);
        }

        // ---- 4. relu + atomics ----
#pragma unroll
        for (int i = 0; i < 4; ++i) {
            const int s = ss[i];
            const int d = dd[i];
#pragma unroll
            for (int tp = 0; tp < 2; ++tp) {
                const int coff = 32 * tp + 2 * r;
                float m0 = fmaxf(__low2float(gs[i][tp])  + cIn[2 * tp][i]     + beI[2 * tp],     0.0f);
                float m1 = fmaxf(__high2float(gs[i][tp]) + cIn[2 * tp + 1][i] + beI[2 * tp + 1], 0.0f);
                if (m0 != 0.0f || m1 != 0.0f)
                    unsafeAtomicAdd((__half2*)(agg_in + (size_t)d * 64 + coff),
                                    __floats2half2_rn(m0, m1));
                float n0 = fmaxf(__low2float(gd[i][tp])  + cOut[2 * tp][i]     + beO[2 * tp],     0.0f);
                float n1 = fmaxf(__high2float(gd[i][tp]) + cOut[2 * tp + 1][i] + beO[2 * tp + 1], 0.0f);
                if (n0 != 0.0f || n1 != 0.0f)
                    unsafeAtomicAdd((__half2*)(agg_out + (size_t)s * 64 + coff),
                                    __floats2half2_rn(n0, n1));
            }
        }

        if (!more) break;
        av0 = nav0; av1 = nav1; s4 = ns4; d4 = nd4; g = gn;
    }
}

// ---------------------------------------------------------------------------
// Node stage: per 16-node group (one wave):
//   h_dir = gelu_exact((x+agg_dir) @ W1 + b1) @ W2
//   out   = 0.5*(h_out+b2_out) + 0.5*(h_in+b2_in) + x @ Wr + br
// ---------------------------------------------------------------------------
#define T_STRIDE 136

__device__ __forceinline__ void gine_mlp(
    const float* __restrict__ x, const __half* __restrict__ agg,
    const float* __restrict__ W1, const float* __restrict__ b1,
    const float* __restrict__ W2,
    int n0, int r, int h, ushort* Tw, f32x4 hAcc[8])
{
    bf16x8 a0[2];
#pragma unroll
    for (int half_ = 0; half_ < 2; ++half_) {
        const int kb = half_ * 32 + h * 8;
        const float*  xp = x   + (size_t)(n0 + r) * 64 + kb;
        const __half* gp = agg + (size_t)(n0 + r) * 64 + kb;
        float4 x0 = *(const float4*)xp;
        float4 x1 = *(const float4*)(xp + 4);
        __half2 g0 = *(const __half2*)(gp);
        __half2 g1 = *(const __half2*)(gp + 2);
        __half2 g2 = *(const __half2*)(gp + 4);
        __half2 g3 = *(const __half2*)(gp + 6);
        bf16x8 v;
        v[0] = (short)f2bf(x0.x + __low2float(g0));
        v[1] = (short)f2bf(x0.y + __high2float(g0));
        v[2] = (short)f2bf(x0.z + __low2float(g1));
        v[3] = (short)f2bf(x0.w + __high2float(g1));
        v[4] = (short)f2bf(x1.x + __low2float(g2));
        v[5] = (short)f2bf(x1.y + __high2float(g2));
        v[6] = (short)f2bf(x1.z + __low2float(g3));
        v[7] = (short)f2bf(x1.w + __high2float(g3));
        a0[half_] = v;
    }

    __threadfence_block();   // previous users of Tw done before overwrite

    // Layer 1: T = gelu(H0 @ W1 + b1) -> LDS (bf16)
#pragma unroll
    for (int t = 0; t < 8; ++t) {
        const float* w1p = W1 + (h * 8) * 128 + 16 * t + r;
        bf16x8 b0v, b1v;
#pragma unroll
        for (int j = 0; j < 8; ++j) {
            b0v[j] = (short)f2bf(w1p[j * 128]);
            b1v[j] = (short)f2bf(w1p[4096 + j * 128]);
        }
        f32x4 acc = {0.f, 0.f, 0.f, 0.f};
        acc = __builtin_amdgcn_mfma_f32_16x16x32_bf16(a0[0], b0v, acc, 0, 0, 0);
        acc = __builtin_amdgcn_mfma_f32_16x16x32_bf16(a0[1], b1v, acc, 0, 0, 0);
        float bias = b1[16 * t + r];
#pragma unroll
        for (int i = 0; i < 4; ++i) {
            float v = acc[i] + bias;
            float g = 0.5f * v * (1.0f + erff(v * 0.70710678118654752f));
            Tw[(h * 4 + i) * T_STRIDE + 16 * t + r] = f2bf(g);
        }
    }

    __threadfence_block();   // T writes visible before reads

    // Layer 2: h = T @ W2   (b2 added by caller)
    bf16x8 aT[4];
#pragma unroll
    for (int ks = 0; ks < 4; ++ks)
        aT[ks] = *(const bf16x8*)(Tw + r * T_STRIDE + ks * 32 + h * 8);
#pragma unroll
    for (int t = 0; t < 8; ++t) {
        const float* w2p = W2 + (h * 8) * 128 + 16 * t + r;
        f32x4 acc = {0.f, 0.f, 0.f, 0.f};
#pragma unroll
        for (int ks = 0; ks < 4; ++ks) {
            bf16x8 bv;
#pragma unroll
            for (int j = 0; j < 8; ++j) bv[j] = (short)f2bf(w2p[(ks * 32 + j) * 128]);
            acc = __builtin_amdgcn_mfma_f32_16x16x32_bf16(aT[ks], bv, acc, 0, 0, 0);
        }
        hAcc[t] = acc;
    }
}

__global__ __launch_bounds__(256) void node_kernel(
    const float* __restrict__ x,
    const __half* __restrict__ agg_in, const __half* __restrict__ agg_out,
    const float* __restrict__ W1_in, const float* __restrict__ b1_in,
    const float* __restrict__ W2_in, const float* __restrict__ b2_in,
    const float* __restrict__ W1_out, const float* __restrict__ b1_out,
    const float* __restrict__ W2_out, const float* __restrict__ b2_out,
    const float* __restrict__ Wr, const float* __restrict__ br,
    float* __restrict__ out)
{
    const int lane = threadIdx.x & 63;
    const int r = lane & 15;
    const int h = lane >> 4;
    const int wave = threadIdx.x >> 6;

    __shared__ __align__(16) ushort Tld[4][16 * T_STRIDE];
    ushort* Tw = &Tld[wave][0];

    const int g = blockIdx.x * 4 + wave;
    if (g >= N_NODES / 16) return;           // no __syncthreads in this kernel
    const int n0 = g * 16;

    f32x4 hIn[8], hOut[8];
    gine_mlp(x, agg_in,  W1_in,  b1_in,  W2_in,  n0, r, h, Tw, hIn);
    gine_mlp(x, agg_out, W1_out, b1_out, W2_out, n0, r, h, Tw, hOut);

    bf16x8 ar[2];
#pragma unroll
    for (int half_ = 0; half_ < 2; ++half_) {
        const float* xp = x + (size_t)(n0 + r) * 64 + half_ * 32 + h * 8;
        bf16x8 v;
#pragma unroll
        for (int j = 0; j < 8; ++j) v[j] = (short)f2bf(xp[j]);
        ar[half_] = v;
    }

#pragma unroll
    for (int t = 0; t < 8; ++t) {
        const float* wrp = Wr + (h * 8) * 128 + 16 * t + r;
        bf16x8 b0v, b1v;
#pragma unroll
        for (int j = 0; j < 8; ++j) {
            b0v[j] = (short)f2bf(wrp[j * 128]);
            b1v[j] = (short)f2bf(wrp[4096 + j * 128]);
        }
        f32x4 rt = {0.f, 0.f, 0.f, 0.f};
        rt = __builtin_amdgcn_mfma_f32_16x16x32_bf16(ar[0], b0v, rt, 0, 0, 0);
        rt = __builtin_amdgcn_mfma_f32_16x16x32_bf16(ar[1], b1v, rt, 0, 0, 0);

        const int c = 16 * t + r;
        float b2i = b2_in[c];
        float b2o = b2_out[c];
        float brv = br[c];
#pragma unroll
        for (int i = 0; i < 4; ++i) {
            float o = 0.5f * (hOut[t][i] + b2o) + 0.5f * (hIn[t][i] + b2i) + rt[i] + brv;
            out[(size_t)(n0 + h * 4 + i) * 128 + c] = o;
        }
    }
}

extern "C" void kernel_launch(void* const* d_in, const int* in_sizes, int n_in,
                              void* d_out, int out_size, void* d_ws, size_t ws_size,
                              hipStream_t stream) {
    const float* x      = (const float*)d_in[0];
    const int*   ei     = (const int*)d_in[1];
    const float* ea     = (const float*)d_in[2];
    const float* We_in  = (const float*)d_in[3];
    const float* be_in  = (const float*)d_in[4];
    const float* W1_in  = (const float*)d_in[5];
    const float* b1_in  = (const float*)d_in[6];
    const float* W2_in  = (const float*)d_in[7];
    const float* b2_in  = (const float*)d_in[8];
    const float* We_out = (const float*)d_in[9];
    const float* be_out = (const float*)d_in[10];
    const float* W1_out = (const float*)d_in[11];
    const float* b1_out = (const float*)d_in[12];
    const float* W2_out = (const float*)d_in[13];
    const float* b2_out = (const float*)d_in[14];
    const float* Wr     = (const float*)d_in[15];
    const float* br     = (const float*)d_in[16];

    __half* agg_in  = (__half*)d_ws;                      // 12.8 MB
    __half* agg_out = agg_in + (size_t)N_NODES * IN_DIM;  // 12.8 MB
    __half* xh      = agg_out + (size_t)N_NODES * IN_DIM; // 12.8 MB
    const size_t agg_bytes = (size_t)2 * N_NODES * IN_DIM * sizeof(__half);

    hipMemsetAsync(d_ws, 0, agg_bytes, stream);

    cvt_x_kernel<<<(N_NODES * IN_DIM / 4 + 255) / 256, 256, 0, stream>>>(x, xh);

    edge_kernel<<<2048, 256, 0, stream>>>(xh, ei, ea, We_in, be_in, We_out, be_out,
                                          agg_in, agg_out);

    node_kernel<<<(N_NODES / 16 + 3) / 4, 256, 0, stream>>>(
        x, agg_in, agg_out,
        W1_in, b1_in, W2_in, b2_in,
        W1_out, b1_out, W2_out, b2_out,
        Wr, br, (float*)d_out);
}

// Round 5
// 410.027 us; speedup vs baseline: 3.8345x; 1.0682x over previous
//
#include <hip/hip_runtime.h>
#include <hip/hip_bf16.h>
#include <hip/hip_fp16.h>
#include <math.h>

#define N_NODES 100000
#define IN_DIM 64
#define EMBED_DIM 128
#define EDGE_DIM 32
#define N_EDGES 1600000

typedef __attribute__((ext_vector_type(8))) short bf16x8;
typedef __attribute__((ext_vector_type(4))) float f32x4;

__device__ __forceinline__ ushort f2bf(float f) {
    union { float f; uint i; } v; v.f = f;
    uint x = v.i;
    return (ushort)((x + 0x7fffu + ((x >> 16) & 1u)) >> 16);  // RNE
}

// ---------------------------------------------------------------------------
// x -> f16 (halves gather footprint; matches pk_add_f16 layout)
// ---------------------------------------------------------------------------
__global__ __launch_bounds__(256) void cvt_x_kernel(
    const float* __restrict__ x, __half* __restrict__ xh)
{
    const int i = blockIdx.x * blockDim.x + threadIdx.x;
    if (i < N_NODES * IN_DIM / 4) {
        float4 v = ((const float4*)x)[i];
        ((__half2*)xh)[2 * i]     = __floats2half2_rn(v.x, v.y);
        ((__half2*)xh)[2 * i + 1] = __floats2half2_rn(v.z, v.w);
    }
}

// ---------------------------------------------------------------------------
// Weight pre-pack: W1/W2 (both dirs) + Wr -> bf16, FRAGMENT-MAJOR layout so
// the node kernel loads each MFMA B-fragment as one 16-B vector load.
//   W1-type (64x128):  frag(t,hf,h,r,j) -> W[(hf*32+h*8+j)*128 + 16t + r]
//   W2-type (128x128): frag(t,ks,h,r,j) -> W[(ks*32+h*8+j)*128 + 16t + r]
// packed offsets (shorts): w1i=0, w2i=8192, w1o=24576, w2o=32768, wr=49152
// ---------------------------------------------------------------------------
__global__ __launch_bounds__(256) void cvt_w_kernel(
    const float* __restrict__ W1_in, const float* __restrict__ W2_in,
    const float* __restrict__ W1_out, const float* __restrict__ W2_out,
    const float* __restrict__ Wr, ushort* __restrict__ wpk)
{
    const int idx = blockIdx.x * 256 + threadIdx.x;
    if (idx >= 57344) return;
    float v;
    if (idx < 8192) {
        const int k = idx;
        const int j = k & 7, r = (k >> 3) & 15, h = (k >> 7) & 3;
        const int hf = (k >> 9) & 1, t = k >> 10;
        v = W1_in[(hf * 32 + h * 8 + j) * 128 + 16 * t + r];
    } else if (idx < 24576) {
        const int k = idx - 8192;
        const int j = k & 7, r = (k >> 3) & 15, h = (k >> 7) & 3;
        const int ks = (k >> 9) & 3, t = k >> 11;
        v = W2_in[(ks * 32 + h * 8 + j) * 128 + 16 * t + r];
    } else if (idx < 32768) {
        const int k = idx - 24576;
        const int j = k & 7, r = (k >> 3) & 15, h = (k >> 7) & 3;
        const int hf = (k >> 9) & 1, t = k >> 10;
        v = W1_out[(hf * 32 + h * 8 + j) * 128 + 16 * t + r];
    } else if (idx < 49152) {
        const int k = idx - 32768;
        const int j = k & 7, r = (k >> 3) & 15, h = (k >> 7) & 3;
        const int ks = (k >> 9) & 3, t = k >> 11;
        v = W2_out[(ks * 32 + h * 8 + j) * 128 + 16 * t + r];
    } else {
        const int k = idx - 49152;
        const int j = k & 7, r = (k >> 3) & 15, h = (k >> 7) & 3;
        const int hf = (k >> 9) & 1, t = k >> 10;
        v = Wr[(hf * 32 + h * 8 + j) * 128 + 16 * t + r];
    }
    wpk[idx] = f2bf(v);
}

// ---------------------------------------------------------------------------
// Edge stage (round-4, UNCHANGED — at the measured atomic-line-rate ceiling
// of ~19.3 G 64-B-line RMW/s: 6.4M lines / 331 us):
//   agg_in[dst[e]]  += relu(x[src[e]] + ea[e]@We_in  + be_in)   (f16 atomics)
//   agg_out[src[e]] += relu(x[dst[e]] + ea[e]@We_out + be_out)  (f16 atomics)
// ---------------------------------------------------------------------------
__global__ __launch_bounds__(256) void edge_kernel(
    const __half* __restrict__ xh, const int* __restrict__ ei,
    const float* __restrict__ ea,
    const float* __restrict__ We_in, const float* __restrict__ be_in,
    const float* __restrict__ We_out, const float* __restrict__ be_out,
    __half* __restrict__ agg_in, __half* __restrict__ agg_out)
{
    const int lane = threadIdx.x & 63;
    const int r = lane & 15;
    const int h = lane >> 4;
    const int wave = threadIdx.x >> 6;

    // Preload B fragments (permuted cols cp=(t>>1)*32+2r+(t&1)) + biases
    bf16x8 bIn[4], bOut[4];
    float beI[4], beO[4];
#pragma unroll
    for (int t = 0; t < 4; ++t) {
        const int cp = ((t >> 1) << 5) + (r << 1) + (t & 1);
        const float* p1 = We_in  + (h * 8) * 64 + cp;
        const float* p2 = We_out + (h * 8) * 64 + cp;
        bf16x8 b1v, b2v;
#pragma unroll
        for (int j = 0; j < 8; ++j) {
            b1v[j] = (short)f2bf(p1[j * 64]);
            b2v[j] = (short)f2bf(p2[j * 64]);
        }
        bIn[t] = b1v; bOut[t] = b2v;
        beI[t] = be_in[cp];
        beO[t] = be_out[cp];
    }

    const int nGroups = N_EDGES / 16;
    const int stride = gridDim.x * 4;
    int g = blockIdx.x * 4 + wave;
    if (g >= nGroups) return;

    const float* ap0 = ea + (size_t)(g * 16 + r) * 32 + h * 8;
    float4 av0 = *(const float4*)ap0;
    float4 av1 = *(const float4*)(ap0 + 4);
    int4 s4 = *(const int4*)(ei + g * 16 + h * 4);
    int4 d4 = *(const int4*)(ei + N_EDGES + g * 16 + h * 4);

    while (true) {
        const int gn = g + stride;
        const bool more = gn < nGroups;

        // 1. prefetch next group's ea + ei
        float4 nav0 = av0, nav1 = av1;
        int4 ns4 = s4, nd4 = d4;
        if (more) {
            const float* np = ea + (size_t)(gn * 16 + r) * 32 + h * 8;
            nav0 = *(const float4*)np;
            nav1 = *(const float4*)(np + 4);
            ns4 = *(const int4*)(ei + gn * 16 + h * 4);
            nd4 = *(const int4*)(ei + N_EDGES + gn * 16 + h * 4);
        }

        // 2. issue all xh gathers for current group
        const int ss[4] = {s4.x, s4.y, s4.z, s4.w};
        const int dd[4] = {d4.x, d4.y, d4.z, d4.w};
        __half2 gs[4][2], gd[4][2];
#pragma unroll
        for (int i = 0; i < 4; ++i) {
#pragma unroll
            for (int tp = 0; tp < 2; ++tp) {
                gs[i][tp] = *(const __half2*)(xh + (size_t)ss[i] * 64 + 32 * tp + 2 * r);
                gd[i][tp] = *(const __half2*)(xh + (size_t)dd[i] * 64 + 32 * tp + 2 * r);
            }
        }

        // 3. cvt + MFMA
        bf16x8 a;
        a[0] = (short)f2bf(av0.x); a[1] = (short)f2bf(av0.y);
        a[2] = (short)f2bf(av0.z); a[3] = (short)f2bf(av0.w);
        a[4] = (short)f2bf(av1.x); a[5] = (short)f2bf(av1.y);
        a[6] = (short)f2bf(av1.z); a[7] = (short)f2bf(av1.w);

        f32x4 cIn[4], cOut[4];
#pragma unroll
        for (int t = 0; t < 4; ++t) {
            f32x4 z = {0.f, 0.f, 0.f, 0.f};
            cIn[t]  = __builtin_amdgcn_mfma_f32_16x16x32_bf16(a, bIn[t],  z, 0, 0, 0);
            cOut[t] = __builtin_amdgcn_mfma_f32_16x16x32_bf16(a, bOut[t], z, 0, 0, 0);
        }

        // 4. relu + atomics (non-returning)
#pragma unroll
        for (int i = 0; i < 4; ++i) {
            const int s = ss[i];
            const int d = dd[i];
#pragma unroll
            for (int tp = 0; tp < 2; ++tp) {
                const int coff = 32 * tp + 2 * r;
                float m0 = fmaxf(__low2float(gs[i][tp])  + cIn[2 * tp][i]     + beI[2 * tp],     0.0f);
                float m1 = fmaxf(__high2float(gs[i][tp]) + cIn[2 * tp + 1][i] + beI[2 * tp + 1], 0.0f);
                if (m0 != 0.0f || m1 != 0.0f)
                    unsafeAtomicAdd((__half2*)(agg_in + (size_t)d * 64 + coff),
                                    __floats2half2_rn(m0, m1));
                float n0 = fmaxf(__low2float(gd[i][tp])  + cOut[2 * tp][i]     + beO[2 * tp],     0.0f);
                float n1 = fmaxf(__high2float(gd[i][tp]) + cOut[2 * tp + 1][i] + beO[2 * tp + 1], 0.0f);
                if (n0 != 0.0f || n1 != 0.0f)
                    unsafeAtomicAdd((__half2*)(agg_out + (size_t)s * 64 + coff),
                                    __floats2half2_rn(n0, n1));
            }
        }

        if (!more) break;
        av0 = nav0; av1 = nav1; s4 = ns4; d4 = nd4; g = gn;
    }
}

// ---------------------------------------------------------------------------
// Node stage: weights come pre-packed in bf16 fragment-major layout -> each
// B-fragment is one 16-B load, zero conversion VALU, half the weight bytes.
// ---------------------------------------------------------------------------
#define T_STRIDE 136

__device__ __forceinline__ void gine_mlp(
    const float* __restrict__ x, const __half* __restrict__ agg,
    const ushort* __restrict__ w1f, const float* __restrict__ b1,
    const ushort* __restrict__ w2f,
    int n0, int r, int h, ushort* Tw, f32x4 hAcc[8])
{
    bf16x8 a0[2];
#pragma unroll
    for (int half_ = 0; half_ < 2; ++half_) {
        const int kb = half_ * 32 + h * 8;
        const float*  xp = x   + (size_t)(n0 + r) * 64 + kb;
        const __half* gp = agg + (size_t)(n0 + r) * 64 + kb;
        float4 x0 = *(const float4*)xp;
        float4 x1 = *(const float4*)(xp + 4);
        __half2 g0 = *(const __half2*)(gp);
        __half2 g1 = *(const __half2*)(gp + 2);
        __half2 g2 = *(const __half2*)(gp + 4);
        __half2 g3 = *(const __half2*)(gp + 6);
        bf16x8 v;
        v[0] = (short)f2bf(x0.x + __low2float(g0));
        v[1] = (short)f2bf(x0.y + __high2float(g0));
        v[2] = (short)f2bf(x0.z + __low2float(g1));
        v[3] = (short)f2bf(x0.w + __high2float(g1));
        v[4] = (short)f2bf(x1.x + __low2float(g2));
        v[5] = (short)f2bf(x1.y + __high2float(g2));
        v[6] = (short)f2bf(x1.z + __low2float(g3));
        v[7] = (short)f2bf(x1.w + __high2float(g3));
        a0[half_] = v;
    }

    __threadfence_block();   // previous users of Tw done before overwrite

    // Layer 1: T = gelu(H0 @ W1 + b1) -> LDS (bf16)
#pragma unroll
    for (int t = 0; t < 8; ++t) {
        const bf16x8 b0v = *(const bf16x8*)(w1f + (size_t)(((t * 2 + 0) * 4 + h) * 16 + r) * 8);
        const bf16x8 b1v = *(const bf16x8*)(w1f + (size_t)(((t * 2 + 1) * 4 + h) * 16 + r) * 8);
        f32x4 acc = {0.f, 0.f, 0.f, 0.f};
        acc = __builtin_amdgcn_mfma_f32_16x16x32_bf16(a0[0], b0v, acc, 0, 0, 0);
        acc = __builtin_amdgcn_mfma_f32_16x16x32_bf16(a0[1], b1v, acc, 0, 0, 0);
        float bias = b1[16 * t + r];
#pragma unroll
        for (int i = 0; i < 4; ++i) {
            float v = acc[i] + bias;
            float g = 0.5f * v * (1.0f + erff(v * 0.70710678118654752f));
            Tw[(h * 4 + i) * T_STRIDE + 16 * t + r] = f2bf(g);
        }
    }

    __threadfence_block();   // T writes visible before reads

    // Layer 2: h = T @ W2   (b2 added by caller)
    bf16x8 aT[4];
#pragma unroll
    for (int ks = 0; ks < 4; ++ks)
        aT[ks] = *(const bf16x8*)(Tw + r * T_STRIDE + ks * 32 + h * 8);
#pragma unroll
    for (int t = 0; t < 8; ++t) {
        f32x4 acc = {0.f, 0.f, 0.f, 0.f};
#pragma unroll
        for (int ks = 0; ks < 4; ++ks) {
            const bf16x8 bv = *(const bf16x8*)(w2f + (size_t)(((t * 4 + ks) * 4 + h) * 16 + r) * 8);
            acc = __builtin_amdgcn_mfma_f32_16x16x32_bf16(aT[ks], bv, acc, 0, 0, 0);
        }
        hAcc[t] = acc;
    }
}

__global__ __launch_bounds__(256) void node_kernel(
    const float* __restrict__ x,
    const __half* __restrict__ agg_in, const __half* __restrict__ agg_out,
    const ushort* __restrict__ wpk,
    const float* __restrict__ b1_in, const float* __restrict__ b2_in,
    const float* __restrict__ b1_out, const float* __restrict__ b2_out,
    const float* __restrict__ br,
    float* __restrict__ out)
{
    const int lane = threadIdx.x & 63;
    const int r = lane & 15;
    const int h = lane >> 4;
    const int wave = threadIdx.x >> 6;

    __shared__ __align__(16) ushort Tld[4][16 * T_STRIDE];
    ushort* Tw = &Tld[wave][0];

    const int g = blockIdx.x * 4 + wave;
    if (g >= N_NODES / 16) return;           // no __syncthreads in this kernel
    const int n0 = g * 16;

    const ushort* w1i = wpk;
    const ushort* w2i = wpk + 8192;
    const ushort* w1o = wpk + 24576;
    const ushort* w2o = wpk + 32768;
    const ushort* wrf = wpk + 49152;

    f32x4 hIn[8], hOut[8];
    gine_mlp(x, agg_in,  w1i, b1_in,  w2i, n0, r, h, Tw, hIn);
    gine_mlp(x, agg_out, w1o, b1_out, w2o, n0, r, h, Tw, hOut);

    bf16x8 ar[2];
#pragma unroll
    for (int half_ = 0; half_ < 2; ++half_) {
        const float* xp = x + (size_t)(n0 + r) * 64 + half_ * 32 + h * 8;
        bf16x8 v;
#pragma unroll
        for (int j = 0; j < 8; ++j) v[j] = (short)f2bf(xp[j]);
        ar[half_] = v;
    }

#pragma unroll
    for (int t = 0; t < 8; ++t) {
        const bf16x8 b0v = *(const bf16x8*)(wrf + (size_t)(((t * 2 + 0) * 4 + h) * 16 + r) * 8);
        const bf16x8 b1v = *(const bf16x8*)(wrf + (size_t)(((t * 2 + 1) * 4 + h) * 16 + r) * 8);
        f32x4 rt = {0.f, 0.f, 0.f, 0.f};
        rt = __builtin_amdgcn_mfma_f32_16x16x32_bf16(ar[0], b0v, rt, 0, 0, 0);
        rt = __builtin_amdgcn_mfma_f32_16x16x32_bf16(ar[1], b1v, rt, 0, 0, 0);

        const int c = 16 * t + r;
        float b2i = b2_in[c];
        float b2o = b2_out[c];
        float brv = br[c];
#pragma unroll
        for (int i = 0; i < 4; ++i) {
            float o = 0.5f * (hOut[t][i] + b2o) + 0.5f * (hIn[t][i] + b2i) + rt[i] + brv;
            out[(size_t)(n0 + h * 4 + i) * 128 + c] = o;
        }
    }
}

extern "C" void kernel_launch(void* const* d_in, const int* in_sizes, int n_in,
                              void* d_out, int out_size, void* d_ws, size_t ws_size,
                              hipStream_t stream) {
    const float* x      = (const float*)d_in[0];
    const int*   ei     = (const int*)d_in[1];
    const float* ea     = (const float*)d_in[2];
    const float* We_in  = (const float*)d_in[3];
    const float* be_in  = (const float*)d_in[4];
    const float* W1_in  = (const float*)d_in[5];
    const float* b1_in  = (const float*)d_in[6];
    const float* W2_in  = (const float*)d_in[7];
    const float* b2_in  = (const float*)d_in[8];
    const float* We_out = (const float*)d_in[9];
    const float* be_out = (const float*)d_in[10];
    const float* W1_out = (const float*)d_in[11];
    const float* b1_out = (const float*)d_in[12];
    const float* W2_out = (const float*)d_in[13];
    const float* b2_out = (const float*)d_in[14];
    const float* Wr     = (const float*)d_in[15];
    const float* br     = (const float*)d_in[16];

    __half* agg_in  = (__half*)d_ws;                      // 12.8 MB
    __half* agg_out = agg_in + (size_t)N_NODES * IN_DIM;  // 12.8 MB
    __half* xh      = agg_out + (size_t)N_NODES * IN_DIM; // 12.8 MB
    ushort* wpk     = (ushort*)(xh + (size_t)N_NODES * IN_DIM);  // 112 KB
    const size_t agg_bytes = (size_t)2 * N_NODES * IN_DIM * sizeof(__half);

    hipMemsetAsync(d_ws, 0, agg_bytes, stream);

    cvt_x_kernel<<<(N_NODES * IN_DIM / 4 + 255) / 256, 256, 0, stream>>>(x, xh);
    cvt_w_kernel<<<(57344 + 255) / 256, 256, 0, stream>>>(
        W1_in, W2_in, W1_out, W2_out, Wr, wpk);

    edge_kernel<<<2048, 256, 0, stream>>>(xh, ei, ea, We_in, be_in, We_out, be_out,
                                          agg_in, agg_out);

    node_kernel<<<(N_NODES / 16 + 3) / 4, 256, 0, stream>>>(
        x, agg_in, agg_out, wpk,
        b1_in, b2_in, b1_out, b2_out, br, (float*)d_out);
}

// Round 6
// 401.615 us; speedup vs baseline: 3.9149x; 1.0209x over previous
//
#include <hip/hip_runtime.h>
#include <hip/hip_bf16.h>
#include <hip/hip_fp16.h>
#include <math.h>

#define N_NODES 100000
#define IN_DIM 64
#define EMBED_DIM 128
#define EDGE_DIM 32
#define N_EDGES 1600000

typedef __attribute__((ext_vector_type(8))) short bf16x8;
typedef __attribute__((ext_vector_type(4))) float f32x4;

__device__ __forceinline__ ushort f2bf(float f) {
    union { float f; uint i; } v; v.f = f;
    uint x = v.i;
    return (ushort)((x + 0x7fffu + ((x >> 16) & 1u)) >> 16);  // RNE
}

// ---------------------------------------------------------------------------
// Fused prep: (A) zero agg_in+agg_out (25.6 MB), (B) x -> f16 (12.8 MB),
// (C) weight pre-pack W1/W2 (both dirs) + Wr -> bf16 fragment-major so the
// node kernel loads each MFMA B-fragment as one 16-B vector load.
//   W1-type (64x128):  frag(t,hf,h,r,j) -> W[(hf*32+h*8+j)*128 + 16t + r]
//   W2-type (128x128): frag(t,ks,h,r,j) -> W[(ks*32+h*8+j)*128 + 16t + r]
// packed offsets (shorts): w1i=0, w2i=8192, w1o=24576, w2o=32768, wr=49152
// ---------------------------------------------------------------------------
#define PREP_NZ (N_NODES * IN_DIM * 4 / 16)   // 1,600,000 uint4 zero-stores
#define PREP_NX (N_NODES * IN_DIM / 4)        // 1,600,000 float4 cvt items
#define PREP_NW 57344

__global__ __launch_bounds__(256) void prep_kernel(
    const float* __restrict__ x, __half* __restrict__ xh,
    uint4* __restrict__ aggz,
    const float* __restrict__ W1_in, const float* __restrict__ W2_in,
    const float* __restrict__ W1_out, const float* __restrict__ W2_out,
    const float* __restrict__ Wr, ushort* __restrict__ wpk)
{
    const int total = PREP_NZ + PREP_NX + PREP_NW;
    for (int i = blockIdx.x * 256 + threadIdx.x; i < total; i += gridDim.x * 256) {
        if (i < PREP_NZ) {
            aggz[i] = make_uint4(0u, 0u, 0u, 0u);
        } else if (i < PREP_NZ + PREP_NX) {
            const int k = i - PREP_NZ;
            float4 v = ((const float4*)x)[k];
            ((__half2*)xh)[2 * k]     = __floats2half2_rn(v.x, v.y);
            ((__half2*)xh)[2 * k + 1] = __floats2half2_rn(v.z, v.w);
        } else {
            const int idx = i - PREP_NZ - PREP_NX;
            float v;
            if (idx < 8192) {
                const int k = idx;
                const int j = k & 7, r = (k >> 3) & 15, h = (k >> 7) & 3;
                const int hf = (k >> 9) & 1, t = k >> 10;
                v = W1_in[(hf * 32 + h * 8 + j) * 128 + 16 * t + r];
            } else if (idx < 24576) {
                const int k = idx - 8192;
                const int j = k & 7, r = (k >> 3) & 15, h = (k >> 7) & 3;
                const int ks = (k >> 9) & 3, t = k >> 11;
                v = W2_in[(ks * 32 + h * 8 + j) * 128 + 16 * t + r];
            } else if (idx < 32768) {
                const int k = idx - 24576;
                const int j = k & 7, r = (k >> 3) & 15, h = (k >> 7) & 3;
                const int hf = (k >> 9) & 1, t = k >> 10;
                v = W1_out[(hf * 32 + h * 8 + j) * 128 + 16 * t + r];
            } else if (idx < 49152) {
                const int k = idx - 32768;
                const int j = k & 7, r = (k >> 3) & 15, h = (k >> 7) & 3;
                const int ks = (k >> 9) & 3, t = k >> 11;
                v = W2_out[(ks * 32 + h * 8 + j) * 128 + 16 * t + r];
            } else {
                const int k = idx - 49152;
                const int j = k & 7, r = (k >> 3) & 15, h = (k >> 7) & 3;
                const int hf = (k >> 9) & 1, t = k >> 10;
                v = Wr[(hf * 32 + h * 8 + j) * 128 + 16 * t + r];
            }
            wpk[idx] = f2bf(v);
        }
    }
}

// ---------------------------------------------------------------------------
// Edge stage (UNCHANGED — at the measured memory-side atomic-RMW ceiling:
// three structures converge at ~19.3 G 64-B-line RMW/s; 6.4M lines = 331 us;
// WRITE_SIZE == exact atomic bytes, zero line merging):
//   agg_in[dst[e]]  += relu(x[src[e]] + ea[e]@We_in  + be_in)   (f16 atomics)
//   agg_out[src[e]] += relu(x[dst[e]] + ea[e]@We_out + be_out)  (f16 atomics)
// ---------------------------------------------------------------------------
__global__ __launch_bounds__(256) void edge_kernel(
    const __half* __restrict__ xh, const int* __restrict__ ei,
    const float* __restrict__ ea,
    const float* __restrict__ We_in, const float* __restrict__ be_in,
    const float* __restrict__ We_out, const float* __restrict__ be_out,
    __half* __restrict__ agg_in, __half* __restrict__ agg_out)
{
    const int lane = threadIdx.x & 63;
    const int r = lane & 15;
    const int h = lane >> 4;
    const int wave = threadIdx.x >> 6;

    // Preload B fragments (permuted cols cp=(t>>1)*32+2r+(t&1)) + biases
    bf16x8 bIn[4], bOut[4];
    float beI[4], beO[4];
#pragma unroll
    for (int t = 0; t < 4; ++t) {
        const int cp = ((t >> 1) << 5) + (r << 1) + (t & 1);
        const float* p1 = We_in  + (h * 8) * 64 + cp;
        const float* p2 = We_out + (h * 8) * 64 + cp;
        bf16x8 b1v, b2v;
#pragma unroll
        for (int j = 0; j < 8; ++j) {
            b1v[j] = (short)f2bf(p1[j * 64]);
            b2v[j] = (short)f2bf(p2[j * 64]);
        }
        bIn[t] = b1v; bOut[t] = b2v;
        beI[t] = be_in[cp];
        beO[t] = be_out[cp];
    }

    const int nGroups = N_EDGES / 16;
    const int stride = gridDim.x * 4;
    int g = blockIdx.x * 4 + wave;
    if (g >= nGroups) return;

    const float* ap0 = ea + (size_t)(g * 16 + r) * 32 + h * 8;
    float4 av0 = *(const float4*)ap0;
    float4 av1 = *(const float4*)(ap0 + 4);
    int4 s4 = *(const int4*)(ei + g * 16 + h * 4);
    int4 d4 = *(const int4*)(ei + N_EDGES + g * 16 + h * 4);

    while (true) {
        const int gn = g + stride;
        const bool more = gn < nGroups;

        // 1. prefetch next group's ea + ei
        float4 nav0 = av0, nav1 = av1;
        int4 ns4 = s4, nd4 = d4;
        if (more) {
            const float* np = ea + (size_t)(gn * 16 + r) * 32 + h * 8;
            nav0 = *(const float4*)np;
            nav1 = *(const float4*)(np + 4);
            ns4 = *(const int4*)(ei + gn * 16 + h * 4);
            nd4 = *(const int4*)(ei + N_EDGES + gn * 16 + h * 4);
        }

        // 2. issue all xh gathers for current group
        const int ss[4] = {s4.x, s4.y, s4.z, s4.w};
        const int dd[4] = {d4.x, d4.y, d4.z, d4.w};
        __half2 gs[4][2], gd[4][2];
#pragma unroll
        for (int i = 0; i < 4; ++i) {
#pragma unroll
            for (int tp = 0; tp < 2; ++tp) {
                gs[i][tp] = *(const __half2*)(xh + (size_t)ss[i] * 64 + 32 * tp + 2 * r);
                gd[i][tp] = *(const __half2*)(xh + (size_t)dd[i] * 64 + 32 * tp + 2 * r);
            }
        }

        // 3. cvt + MFMA
        bf16x8 a;
        a[0] = (short)f2bf(av0.x); a[1] = (short)f2bf(av0.y);
        a[2] = (short)f2bf(av0.z); a[3] = (short)f2bf(av0.w);
        a[4] = (short)f2bf(av1.x); a[5] = (short)f2bf(av1.y);
        a[6] = (short)f2bf(av1.z); a[7] = (short)f2bf(av1.w);

        f32x4 cIn[4], cOut[4];
#pragma unroll
        for (int t = 0; t < 4; ++t) {
            f32x4 z = {0.f, 0.f, 0.f, 0.f};
            cIn[t]  = __builtin_amdgcn_mfma_f32_16x16x32_bf16(a, bIn[t],  z, 0, 0, 0);
            cOut[t] = __builtin_amdgcn_mfma_f32_16x16x32_bf16(a, bOut[t], z, 0, 0, 0);
        }

        // 4. relu + atomics (non-returning)
#pragma unroll
        for (int i = 0; i < 4; ++i) {
            const int s = ss[i];
            const int d = dd[i];
#pragma unroll
            for (int tp = 0; tp < 2; ++tp) {
                const int coff = 32 * tp + 2 * r;
                float m0 = fmaxf(__low2float(gs[i][tp])  + cIn[2 * tp][i]     + beI[2 * tp],     0.0f);
                float m1 = fmaxf(__high2float(gs[i][tp]) + cIn[2 * tp + 1][i] + beI[2 * tp + 1], 0.0f);
                if (m0 != 0.0f || m1 != 0.0f)
                    unsafeAtomicAdd((__half2*)(agg_in + (size_t)d * 64 + coff),
                                    __floats2half2_rn(m0, m1));
                float n0 = fmaxf(__low2float(gd[i][tp])  + cOut[2 * tp][i]     + beO[2 * tp],     0.0f);
                float n1 = fmaxf(__high2float(gd[i][tp]) + cOut[2 * tp + 1][i] + beO[2 * tp + 1], 0.0f);
                if (n0 != 0.0f || n1 != 0.0f)
                    unsafeAtomicAdd((__half2*)(agg_out + (size_t)s * 64 + coff),
                                    __floats2half2_rn(n0, n1));
            }
        }

        if (!more) break;
        av0 = nav0; av1 = nav1; s4 = ns4; d4 = nd4; g = gn;
    }
}

// ---------------------------------------------------------------------------
// Node stage: pre-packed bf16 fragment-major weights (one 16-B load per
// B-fragment). Each direction gets its OWN LDS T-buffer so the two gine_mlp
// bodies have no inter-direction fence and can interleave (latency hiding).
// ---------------------------------------------------------------------------
#define T_STRIDE 136

__device__ __forceinline__ void gine_mlp(
    const float* __restrict__ x, const __half* __restrict__ agg,
    const ushort* __restrict__ w1f, const float* __restrict__ b1,
    const ushort* __restrict__ w2f,
    int n0, int r, int h, ushort* Tw, f32x4 hAcc[8])
{
    bf16x8 a0[2];
#pragma unroll
    for (int half_ = 0; half_ < 2; ++half_) {
        const int kb = half_ * 32 + h * 8;
        const float*  xp = x   + (size_t)(n0 + r) * 64 + kb;
        const __half* gp = agg + (size_t)(n0 + r) * 64 + kb;
        float4 x0 = *(const float4*)xp;
        float4 x1 = *(const float4*)(xp + 4);
        __half2 g0 = *(const __half2*)(gp);
        __half2 g1 = *(const __half2*)(gp + 2);
        __half2 g2 = *(const __half2*)(gp + 4);
        __half2 g3 = *(const __half2*)(gp + 6);
        bf16x8 v;
        v[0] = (short)f2bf(x0.x + __low2float(g0));
        v[1] = (short)f2bf(x0.y + __high2float(g0));
        v[2] = (short)f2bf(x0.z + __low2float(g1));
        v[3] = (short)f2bf(x0.w + __high2float(g1));
        v[4] = (short)f2bf(x1.x + __low2float(g2));
        v[5] = (short)f2bf(x1.y + __high2float(g2));
        v[6] = (short)f2bf(x1.z + __low2float(g3));
        v[7] = (short)f2bf(x1.w + __high2float(g3));
        a0[half_] = v;
    }

    // Layer 1: T = gelu(H0 @ W1 + b1) -> LDS (bf16)
#pragma unroll
    for (int t = 0; t < 8; ++t) {
        const bf16x8 b0v = *(const bf16x8*)(w1f + (size_t)(((t * 2 + 0) * 4 + h) * 16 + r) * 8);
        const bf16x8 b1v = *(const bf16x8*)(w1f + (size_t)(((t * 2 + 1) * 4 + h) * 16 + r) * 8);
        f32x4 acc = {0.f, 0.f, 0.f, 0.f};
        acc = __builtin_amdgcn_mfma_f32_16x16x32_bf16(a0[0], b0v, acc, 0, 0, 0);
        acc = __builtin_amdgcn_mfma_f32_16x16x32_bf16(a0[1], b1v, acc, 0, 0, 0);
        float bias = b1[16 * t + r];
#pragma unroll
        for (int i = 0; i < 4; ++i) {
            float v = acc[i] + bias;
            float g = 0.5f * v * (1.0f + erff(v * 0.70710678118654752f));
            Tw[(h * 4 + i) * T_STRIDE + 16 * t + r] = f2bf(g);
        }
    }

    __threadfence_block();   // T writes visible before cross-lane reads

    // Layer 2: h = T @ W2   (b2 added by caller)
    bf16x8 aT[4];
#pragma unroll
    for (int ks = 0; ks < 4; ++ks)
        aT[ks] = *(const bf16x8*)(Tw + r * T_STRIDE + ks * 32 + h * 8);
#pragma unroll
    for (int t = 0; t < 8; ++t) {
        f32x4 acc = {0.f, 0.f, 0.f, 0.f};
#pragma unroll
        for (int ks = 0; ks < 4; ++ks) {
            const bf16x8 bv = *(const bf16x8*)(w2f + (size_t)(((t * 4 + ks) * 4 + h) * 16 + r) * 8);
            acc = __builtin_amdgcn_mfma_f32_16x16x32_bf16(aT[ks], bv, acc, 0, 0, 0);
        }
        hAcc[t] = acc;
    }
}

__global__ __launch_bounds__(256) void node_kernel(
    const float* __restrict__ x,
    const __half* __restrict__ agg_in, const __half* __restrict__ agg_out,
    const ushort* __restrict__ wpk,
    const float* __restrict__ b1_in, const float* __restrict__ b2_in,
    const float* __restrict__ b1_out, const float* __restrict__ b2_out,
    const float* __restrict__ br,
    float* __restrict__ out)
{
    const int lane = threadIdx.x & 63;
    const int r = lane & 15;
    const int h = lane >> 4;
    const int wave = threadIdx.x >> 6;

    __shared__ __align__(16) ushort Tld[4][2][16 * T_STRIDE];   // 34.8 KB

    const int g = blockIdx.x * 4 + wave;
    if (g >= N_NODES / 16) return;           // no __syncthreads in this kernel
    const int n0 = g * 16;

    const ushort* w1i = wpk;
    const ushort* w2i = wpk + 8192;
    const ushort* w1o = wpk + 24576;
    const ushort* w2o = wpk + 32768;
    const ushort* wrf = wpk + 49152;

    f32x4 hIn[8], hOut[8];
    gine_mlp(x, agg_in,  w1i, b1_in,  w2i, n0, r, h, &Tld[wave][0][0], hIn);
    gine_mlp(x, agg_out, w1o, b1_out, w2o, n0, r, h, &Tld[wave][1][0], hOut);

    bf16x8 ar[2];
#pragma unroll
    for (int half_ = 0; half_ < 2; ++half_) {
        const float* xp = x + (size_t)(n0 + r) * 64 + half_ * 32 + h * 8;
        bf16x8 v;
#pragma unroll
        for (int j = 0; j < 8; ++j) v[j] = (short)f2bf(xp[j]);
        ar[half_] = v;
    }

#pragma unroll
    for (int t = 0; t < 8; ++t) {
        const bf16x8 b0v = *(const bf16x8*)(wrf + (size_t)(((t * 2 + 0) * 4 + h) * 16 + r) * 8);
        const bf16x8 b1v = *(const bf16x8*)(wrf + (size_t)(((t * 2 + 1) * 4 + h) * 16 + r) * 8);
        f32x4 rt = {0.f, 0.f, 0.f, 0.f};
        rt = __builtin_amdgcn_mfma_f32_16x16x32_bf16(ar[0], b0v, rt, 0, 0, 0);
        rt = __builtin_amdgcn_mfma_f32_16x16x32_bf16(ar[1], b1v, rt, 0, 0, 0);

        const int c = 16 * t + r;
        float b2i = b2_in[c];
        float b2o = b2_out[c];
        float brv = br[c];
#pragma unroll
        for (int i = 0; i < 4; ++i) {
            float o = 0.5f * (hOut[t][i] + b2o) + 0.5f * (hIn[t][i] + b2i) + rt[i] + brv;
            out[(size_t)(n0 + h * 4 + i) * 128 + c] = o;
        }
    }
}

extern "C" void kernel_launch(void* const* d_in, const int* in_sizes, int n_in,
                              void* d_out, int out_size, void* d_ws, size_t ws_size,
                              hipStream_t stream) {
    const float* x      = (const float*)d_in[0];
    const int*   ei     = (const int*)d_in[1];
    const float* ea     = (const float*)d_in[2];
    const float* We_in  = (const float*)d_in[3];
    const float* be_in  = (const float*)d_in[4];
    const float* W1_in  = (const float*)d_in[5];
    const float* b1_in  = (const float*)d_in[6];
    const float* W2_in  = (const float*)d_in[7];
    const float* b2_in  = (const float*)d_in[8];
    const float* We_out = (const float*)d_in[9];
    const float* be_out = (const float*)d_in[10];
    const float* W1_out = (const float*)d_in[11];
    const float* b1_out = (const float*)d_in[12];
    const float* W2_out = (const float*)d_in[13];
    const float* b2_out = (const float*)d_in[14];
    const float* Wr     = (const float*)d_in[15];
    const float* br     = (const float*)d_in[16];

    __half* agg_in  = (__half*)d_ws;                      // 12.8 MB
    __half* agg_out = agg_in + (size_t)N_NODES * IN_DIM;  // 12.8 MB
    __half* xh      = agg_out + (size_t)N_NODES * IN_DIM; // 12.8 MB
    ushort* wpk     = (ushort*)(xh + (size_t)N_NODES * IN_DIM);  // 112 KB

    prep_kernel<<<4096, 256, 0, stream>>>(x, xh, (uint4*)d_ws,
                                          W1_in, W2_in, W1_out, W2_out, Wr, wpk);

    edge_kernel<<<2048, 256, 0, stream>>>(xh, ei, ea, We_in, be_in, We_out, be_out,
                                          agg_in, agg_out);

    node_kernel<<<(N_NODES / 16 + 3) / 4, 256, 0, stream>>>(
        x, agg_in, agg_out, wpk,
        b1_in, b2_in, b1_out, b2_out, br, (float*)d_out);
}

// Round 7
// 400.303 us; speedup vs baseline: 3.9277x; 1.0033x over previous
//
#include <hip/hip_runtime.h>
#include <hip/hip_bf16.h>
#include <hip/hip_fp16.h>
#include <math.h>

#define N_NODES 100000
#define IN_DIM 64
#define EMBED_DIM 128
#define EDGE_DIM 32
#define N_EDGES 1600000

typedef __attribute__((ext_vector_type(8))) short bf16x8;
typedef __attribute__((ext_vector_type(4))) float f32x4;

__device__ __forceinline__ ushort f2bf(float f) {
    union { float f; uint i; } v; v.f = f;
    uint x = v.i;
    return (ushort)((x + 0x7fffu + ((x >> 16) & 1u)) >> 16);  // RNE
}

// ---------------------------------------------------------------------------
// Fused prep: (A) zero agg_in+agg_out (25.6 MB), (B) x -> f16 (12.8 MB),
// (C) weight pre-pack W1/W2 (both dirs) + Wr -> bf16 fragment-major so the
// node kernel loads each MFMA B-fragment as one 16-B vector load.
//   W1-type (64x128):  frag(t,hf,h,r,j) -> W[(hf*32+h*8+j)*128 + 16t + r]
//   W2-type (128x128): frag(t,ks,h,r,j) -> W[(ks*32+h*8+j)*128 + 16t + r]
// packed offsets (shorts): w1i=0, w2i=8192, w1o=24576, w2o=32768, wr=49152
// ---------------------------------------------------------------------------
#define PREP_NZ (N_NODES * IN_DIM * 4 / 16)   // 1,600,000 uint4 zero-stores
#define PREP_NX (N_NODES * IN_DIM / 4)        // 1,600,000 float4 cvt items
#define PREP_NW 57344

__global__ __launch_bounds__(256) void prep_kernel(
    const float* __restrict__ x, __half* __restrict__ xh,
    uint4* __restrict__ aggz,
    const float* __restrict__ W1_in, const float* __restrict__ W2_in,
    const float* __restrict__ W1_out, const float* __restrict__ W2_out,
    const float* __restrict__ Wr, ushort* __restrict__ wpk)
{
    const int total = PREP_NZ + PREP_NX + PREP_NW;
    for (int i = blockIdx.x * 256 + threadIdx.x; i < total; i += gridDim.x * 256) {
        if (i < PREP_NZ) {
            aggz[i] = make_uint4(0u, 0u, 0u, 0u);
        } else if (i < PREP_NZ + PREP_NX) {
            const int k = i - PREP_NZ;
            float4 v = ((const float4*)x)[k];
            ((__half2*)xh)[2 * k]     = __floats2half2_rn(v.x, v.y);
            ((__half2*)xh)[2 * k + 1] = __floats2half2_rn(v.z, v.w);
        } else {
            const int idx = i - PREP_NZ - PREP_NX;
            float v;
            if (idx < 8192) {
                const int k = idx;
                const int j = k & 7, r = (k >> 3) & 15, h = (k >> 7) & 3;
                const int hf = (k >> 9) & 1, t = k >> 10;
                v = W1_in[(hf * 32 + h * 8 + j) * 128 + 16 * t + r];
            } else if (idx < 24576) {
                const int k = idx - 8192;
                const int j = k & 7, r = (k >> 3) & 15, h = (k >> 7) & 3;
                const int ks = (k >> 9) & 3, t = k >> 11;
                v = W2_in[(ks * 32 + h * 8 + j) * 128 + 16 * t + r];
            } else if (idx < 32768) {
                const int k = idx - 24576;
                const int j = k & 7, r = (k >> 3) & 15, h = (k >> 7) & 3;
                const int hf = (k >> 9) & 1, t = k >> 10;
                v = W1_out[(hf * 32 + h * 8 + j) * 128 + 16 * t + r];
            } else if (idx < 49152) {
                const int k = idx - 32768;
                const int j = k & 7, r = (k >> 3) & 15, h = (k >> 7) & 3;
                const int ks = (k >> 9) & 3, t = k >> 11;
                v = W2_out[(ks * 32 + h * 8 + j) * 128 + 16 * t + r];
            } else {
                const int k = idx - 49152;
                const int j = k & 7, r = (k >> 3) & 15, h = (k >> 7) & 3;
                const int hf = (k >> 9) & 1, t = k >> 10;
                v = Wr[(hf * 32 + h * 8 + j) * 128 + 16 * t + r];
            }
            wpk[idx] = f2bf(v);
        }
    }
}

// ---------------------------------------------------------------------------
// Edge stage (UNCHANGED — at the measured memory-side atomic-RMW ceiling:
// three structures converge at ~19.3 G 64-B-line RMW/s; 6.4M lines = 331 us;
// WRITE_SIZE == exact atomic bytes, zero line merging):
//   agg_in[dst[e]]  += relu(x[src[e]] + ea[e]@We_in  + be_in)   (f16 atomics)
//   agg_out[src[e]] += relu(x[dst[e]] + ea[e]@We_out + be_out)  (f16 atomics)
// ---------------------------------------------------------------------------
__global__ __launch_bounds__(256) void edge_kernel(
    const __half* __restrict__ xh, const int* __restrict__ ei,
    const float* __restrict__ ea,
    const float* __restrict__ We_in, const float* __restrict__ be_in,
    const float* __restrict__ We_out, const float* __restrict__ be_out,
    __half* __restrict__ agg_in, __half* __restrict__ agg_out)
{
    const int lane = threadIdx.x & 63;
    const int r = lane & 15;
    const int h = lane >> 4;
    const int wave = threadIdx.x >> 6;

    // Preload B fragments (permuted cols cp=(t>>1)*32+2r+(t&1)) + biases
    bf16x8 bIn[4], bOut[4];
    float beI[4], beO[4];
#pragma unroll
    for (int t = 0; t < 4; ++t) {
        const int cp = ((t >> 1) << 5) + (r << 1) + (t & 1);
        const float* p1 = We_in  + (h * 8) * 64 + cp;
        const float* p2 = We_out + (h * 8) * 64 + cp;
        bf16x8 b1v, b2v;
#pragma unroll
        for (int j = 0; j < 8; ++j) {
            b1v[j] = (short)f2bf(p1[j * 64]);
            b2v[j] = (short)f2bf(p2[j * 64]);
        }
        bIn[t] = b1v; bOut[t] = b2v;
        beI[t] = be_in[cp];
        beO[t] = be_out[cp];
    }

    const int nGroups = N_EDGES / 16;
    const int stride = gridDim.x * 4;
    int g = blockIdx.x * 4 + wave;
    if (g >= nGroups) return;

    const float* ap0 = ea + (size_t)(g * 16 + r) * 32 + h * 8;
    float4 av0 = *(const float4*)ap0;
    float4 av1 = *(const float4*)(ap0 + 4);
    int4 s4 = *(const int4*)(ei + g * 16 + h * 4);
    int4 d4 = *(const int4*)(ei + N_EDGES + g * 16 + h * 4);

    while (true) {
        const int gn = g + stride;
        const bool more = gn < nGroups;

        // 1. prefetch next group's ea + ei
        float4 nav0 = av0, nav1 = av1;
        int4 ns4 = s4, nd4 = d4;
        if (more) {
            const float* np = ea + (size_t)(gn * 16 + r) * 32 + h * 8;
            nav0 = *(const float4*)np;
            nav1 = *(const float4*)(np + 4);
            ns4 = *(const int4*)(ei + gn * 16 + h * 4);
            nd4 = *(const int4*)(ei + N_EDGES + gn * 16 + h * 4);
        }

        // 2. issue all xh gathers for current group
        const int ss[4] = {s4.x, s4.y, s4.z, s4.w};
        const int dd[4] = {d4.x, d4.y, d4.z, d4.w};
        __half2 gs[4][2], gd[4][2];
#pragma unroll
        for (int i = 0; i < 4; ++i) {
#pragma unroll
            for (int tp = 0; tp < 2; ++tp) {
                gs[i][tp] = *(const __half2*)(xh + (size_t)ss[i] * 64 + 32 * tp + 2 * r);
                gd[i][tp] = *(const __half2*)(xh + (size_t)dd[i] * 64 + 32 * tp + 2 * r);
            }
        }

        // 3. cvt + MFMA
        bf16x8 a;
        a[0] = (short)f2bf(av0.x); a[1] = (short)f2bf(av0.y);
        a[2] = (short)f2bf(av0.z); a[3] = (short)f2bf(av0.w);
        a[4] = (short)f2bf(av1.x); a[5] = (short)f2bf(av1.y);
        a[6] = (short)f2bf(av1.z); a[7] = (short)f2bf(av1.w);

        f32x4 cIn[4], cOut[4];
#pragma unroll
        for (int t = 0; t < 4; ++t) {
            f32x4 z = {0.f, 0.f, 0.f, 0.f};
            cIn[t]  = __builtin_amdgcn_mfma_f32_16x16x32_bf16(a, bIn[t],  z, 0, 0, 0);
            cOut[t] = __builtin_amdgcn_mfma_f32_16x16x32_bf16(a, bOut[t], z, 0, 0, 0);
        }

        // 4. relu + atomics (non-returning)
#pragma unroll
        for (int i = 0; i < 4; ++i) {
            const int s = ss[i];
            const int d = dd[i];
#pragma unroll
            for (int tp = 0; tp < 2; ++tp) {
                const int coff = 32 * tp + 2 * r;
                float m0 = fmaxf(__low2float(gs[i][tp])  + cIn[2 * tp][i]     + beI[2 * tp],     0.0f);
                float m1 = fmaxf(__high2float(gs[i][tp]) + cIn[2 * tp + 1][i] + beI[2 * tp + 1], 0.0f);
                if (m0 != 0.0f || m1 != 0.0f)
                    unsafeAtomicAdd((__half2*)(agg_in + (size_t)d * 64 + coff),
                                    __floats2half2_rn(m0, m1));
                float n0 = fmaxf(__low2float(gd[i][tp])  + cOut[2 * tp][i]     + beO[2 * tp],     0.0f);
                float n1 = fmaxf(__high2float(gd[i][tp]) + cOut[2 * tp + 1][i] + beO[2 * tp + 1], 0.0f);
                if (n0 != 0.0f || n1 != 0.0f)
                    unsafeAtomicAdd((__half2*)(agg_out + (size_t)s * 64 + coff),
                                    __floats2half2_rn(n0, n1));
            }
        }

        if (!more) break;
        av0 = nav0; av1 = nav1; s4 = ns4; d4 = nd4; g = gn;
    }
}

// ---------------------------------------------------------------------------
// Node stage (single-fence, f16-everywhere):
//   phase A: load all A-fragments (in/out/root from xh+agg) -> layer-1 MFMAs
//            for BOTH directions (independent chains, interleaved) -> T0/T1
//   fence
//   phase B: layer-2 both directions + root MFMA + epilogue
// Node never touches f32 x: reads xh (12.8 MB) + agg (25.6 MB) + packed
// weights (L2-resident), writes out (51.2 MB).
// ---------------------------------------------------------------------------
#define T_STRIDE 136

__global__ __launch_bounds__(256) void node_kernel(
    const __half* __restrict__ xh,
    const __half* __restrict__ agg_in, const __half* __restrict__ agg_out,
    const ushort* __restrict__ wpk,
    const float* __restrict__ b1_in, const float* __restrict__ b2_in,
    const float* __restrict__ b1_out, const float* __restrict__ b2_out,
    const float* __restrict__ br,
    float* __restrict__ out)
{
    const int lane = threadIdx.x & 63;
    const int r = lane & 15;
    const int h = lane >> 4;
    const int wave = threadIdx.x >> 6;

    __shared__ __align__(16) ushort Tld[4][2][16 * T_STRIDE];   // 34.8 KB

    const int g = blockIdx.x * 4 + wave;
    if (g >= N_NODES / 16) return;           // no __syncthreads in this kernel
    const int n0 = g * 16;

    const ushort* w1i = wpk;
    const ushort* w2i = wpk + 8192;
    const ushort* w1o = wpk + 24576;
    const ushort* w2o = wpk + 32768;
    const ushort* wrf = wpk + 49152;

    ushort* T0 = &Tld[wave][0][0];
    ushort* T1 = &Tld[wave][1][0];

    // ---- phase A: all fragment loads (issued together), then layer-1 ----
    bf16x8 aIn[2], aOut[2], ar[2];
#pragma unroll
    for (int hf = 0; hf < 2; ++hf) {
        const int kb = hf * 32 + h * 8;
        const __half2* xp = (const __half2*)(xh      + (size_t)(n0 + r) * 64 + kb);
        const __half2* gi = (const __half2*)(agg_in  + (size_t)(n0 + r) * 64 + kb);
        const __half2* go = (const __half2*)(agg_out + (size_t)(n0 + r) * 64 + kb);
        __half2 xv[4], iv[4], ov[4];
#pragma unroll
        for (int j = 0; j < 4; ++j) { xv[j] = xp[j]; iv[j] = gi[j]; ov[j] = go[j]; }
        bf16x8 vi, vo, vr;
#pragma unroll
        for (int j = 0; j < 4; ++j) {
            const float xl = __low2float(xv[j]), xh_ = __high2float(xv[j]);
            vi[2 * j]     = (short)f2bf(xl  + __low2float(iv[j]));
            vi[2 * j + 1] = (short)f2bf(xh_ + __high2float(iv[j]));
            vo[2 * j]     = (short)f2bf(xl  + __low2float(ov[j]));
            vo[2 * j + 1] = (short)f2bf(xh_ + __high2float(ov[j]));
            vr[2 * j]     = (short)f2bf(xl);
            vr[2 * j + 1] = (short)f2bf(xh_);
        }
        aIn[hf] = vi; aOut[hf] = vo; ar[hf] = vr;
    }

    // layer-1 both directions (independent MFMA chains -> interleaved)
#pragma unroll
    for (int t = 0; t < 8; ++t) {
        const bf16x8 bi0 = *(const bf16x8*)(w1i + (size_t)(((t * 2 + 0) * 4 + h) * 16 + r) * 8);
        const bf16x8 bi1 = *(const bf16x8*)(w1i + (size_t)(((t * 2 + 1) * 4 + h) * 16 + r) * 8);
        const bf16x8 bo0 = *(const bf16x8*)(w1o + (size_t)(((t * 2 + 0) * 4 + h) * 16 + r) * 8);
        const bf16x8 bo1 = *(const bf16x8*)(w1o + (size_t)(((t * 2 + 1) * 4 + h) * 16 + r) * 8);
        f32x4 ci = {0.f, 0.f, 0.f, 0.f};
        f32x4 co = {0.f, 0.f, 0.f, 0.f};
        ci = __builtin_amdgcn_mfma_f32_16x16x32_bf16(aIn[0],  bi0, ci, 0, 0, 0);
        co = __builtin_amdgcn_mfma_f32_16x16x32_bf16(aOut[0], bo0, co, 0, 0, 0);
        ci = __builtin_amdgcn_mfma_f32_16x16x32_bf16(aIn[1],  bi1, ci, 0, 0, 0);
        co = __builtin_amdgcn_mfma_f32_16x16x32_bf16(aOut[1], bo1, co, 0, 0, 0);
        const float bi = b1_in[16 * t + r];
        const float bo = b1_out[16 * t + r];
#pragma unroll
        for (int i = 0; i < 4; ++i) {
            float vi_ = ci[i] + bi;
            float vo_ = co[i] + bo;
            float gi_ = 0.5f * vi_ * (1.0f + erff(vi_ * 0.70710678118654752f));
            float go_ = 0.5f * vo_ * (1.0f + erff(vo_ * 0.70710678118654752f));
            T0[(h * 4 + i) * T_STRIDE + 16 * t + r] = f2bf(gi_);
            T1[(h * 4 + i) * T_STRIDE + 16 * t + r] = f2bf(go_);
        }
    }

    __threadfence_block();   // T writes visible before cross-lane reads

    // ---- phase B: layer-2 both directions + root + epilogue ----
    bf16x8 aT0[4], aT1[4];
#pragma unroll
    for (int ks = 0; ks < 4; ++ks) {
        aT0[ks] = *(const bf16x8*)(T0 + r * T_STRIDE + ks * 32 + h * 8);
        aT1[ks] = *(const bf16x8*)(T1 + r * T_STRIDE + ks * 32 + h * 8);
    }

#pragma unroll
    for (int t = 0; t < 8; ++t) {
        f32x4 ci = {0.f, 0.f, 0.f, 0.f};
        f32x4 co = {0.f, 0.f, 0.f, 0.f};
#pragma unroll
        for (int ks = 0; ks < 4; ++ks) {
            const bf16x8 bi = *(const bf16x8*)(w2i + (size_t)(((t * 4 + ks) * 4 + h) * 16 + r) * 8);
            const bf16x8 bo = *(const bf16x8*)(w2o + (size_t)(((t * 4 + ks) * 4 + h) * 16 + r) * 8);
            ci = __builtin_amdgcn_mfma_f32_16x16x32_bf16(aT0[ks], bi, ci, 0, 0, 0);
            co = __builtin_amdgcn_mfma_f32_16x16x32_bf16(aT1[ks], bo, co, 0, 0, 0);
        }
        const bf16x8 r0 = *(const bf16x8*)(wrf + (size_t)(((t * 2 + 0) * 4 + h) * 16 + r) * 8);
        const bf16x8 r1 = *(const bf16x8*)(wrf + (size_t)(((t * 2 + 1) * 4 + h) * 16 + r) * 8);
        f32x4 rt = {0.f, 0.f, 0.f, 0.f};
        rt = __builtin_amdgcn_mfma_f32_16x16x32_bf16(ar[0], r0, rt, 0, 0, 0);
        rt = __builtin_amdgcn_mfma_f32_16x16x32_bf16(ar[1], r1, rt, 0, 0, 0);

        const int c = 16 * t + r;
        const float b2i = b2_in[c];
        const float b2o = b2_out[c];
        const float brv = br[c];
#pragma unroll
        for (int i = 0; i < 4; ++i) {
            float o = 0.5f * (co[i] + b2o) + 0.5f * (ci[i] + b2i) + rt[i] + brv;
            out[(size_t)(n0 + h * 4 + i) * 128 + c] = o;
        }
    }
}

extern "C" void kernel_launch(void* const* d_in, const int* in_sizes, int n_in,
                              void* d_out, int out_size, void* d_ws, size_t ws_size,
                              hipStream_t stream) {
    const float* x      = (const float*)d_in[0];
    const int*   ei     = (const int*)d_in[1];
    const float* ea     = (const float*)d_in[2];
    const float* We_in  = (const float*)d_in[3];
    const float* be_in  = (const float*)d_in[4];
    const float* W1_in  = (const float*)d_in[5];
    const float* b1_in  = (const float*)d_in[6];
    const float* W2_in  = (const float*)d_in[7];
    const float* b2_in  = (const float*)d_in[8];
    const float* We_out = (const float*)d_in[9];
    const float* be_out = (const float*)d_in[10];
    const float* W1_out = (const float*)d_in[11];
    const float* b1_out = (const float*)d_in[12];
    const float* W2_out = (const float*)d_in[13];
    const float* b2_out = (const float*)d_in[14];
    const float* Wr     = (const float*)d_in[15];
    const float* br     = (const float*)d_in[16];

    __half* agg_in  = (__half*)d_ws;                      // 12.8 MB
    __half* agg_out = agg_in + (size_t)N_NODES * IN_DIM;  // 12.8 MB
    __half* xh      = agg_out + (size_t)N_NODES * IN_DIM; // 12.8 MB
    ushort* wpk     = (ushort*)(xh + (size_t)N_NODES * IN_DIM);  // 112 KB

    prep_kernel<<<4096, 256, 0, stream>>>(x, xh, (uint4*)d_ws,
                                          W1_in, W2_in, W1_out, W2_out, Wr, wpk);

    edge_kernel<<<2048, 256, 0, stream>>>(xh, ei, ea, We_in, be_in, We_out, be_out,
                                          agg_in, agg_out);

    node_kernel<<<(N_NODES / 16 + 3) / 4, 256, 0, stream>>>(
        xh, agg_in, agg_out, wpk,
        b1_in, b2_in, b1_out, b2_out, br, (float*)d_out);
}